// Round 21
// baseline (73.902 us; speedup 1.0000x reference)
//
#include <hip/hip_runtime.h>

// Fused Swin shifted-window MSA, one workgroup (4 waves) per 7x7 window.
// Round 21: single-variable A/B vs round 20 (63.36us): s_setprio REMOVED.
// Rationale (m190): setprio measured NEGATIVE on barrier-synced lockstep
// kernels — T5 needs phase-split wave roles; in a 4-wave lockstep block,
// boosting one wave's MFMA window delays siblings ahead of the shared
// barrier (priority inversion). It entered in the r10 bundle, never
// isolated (r17 bundled its removal with the NaN softmax change).
// Everything else byte-identical to r20: max-pass exp2 softmax (log2e
// folded), defer-norm, stride-140 LDS + b64 frags, paired streams, bias
// double-buffer, out-proj prefetch before barrier 2.

#define HWD 56
#define SCALE_Q 0.17677669529663687f   // 1/sqrt(32)
#define LOG2E   1.4426950408889634f
#define XS 140                          // LDS row stride in halves (70 words)

typedef _Float16 f16x8 __attribute__((ext_vector_type(8)));
typedef __fp16   h16x2 __attribute__((ext_vector_type(2)));   // cvt_pkrtz return type
typedef float    f32x4 __attribute__((ext_vector_type(4)));

__device__ __forceinline__ unsigned pkrtz(float a, float b) {
    union { h16x2 h; unsigned u; } r;
    r.h = __builtin_amdgcn_cvt_pkrtz(a, b);
    return r.u;
}

__device__ __forceinline__ float exp2fast(float x) {   // v_exp_f32: D = 2^S0
    float r;
    asm("v_exp_f32 %0, %1" : "=v"(r) : "v"(x));
    return r;
}

__device__ __forceinline__ f32x4 mfma16(const unsigned a[4], const unsigned b[4], f32x4 c) {
    union { unsigned u[4]; f16x8 h; } A, B;
    A.u[0] = a[0]; A.u[1] = a[1]; A.u[2] = a[2]; A.u[3] = a[3];
    B.u[0] = b[0]; B.u[1] = b[1]; B.u[2] = b[2]; B.u[3] = b[3];
    return __builtin_amdgcn_mfma_f32_16x16x32_f16(A.h, B.h, c, 0, 0, 0);
}

__device__ __forceinline__ unsigned short f16b(float v) {
    union { _Float16 h; unsigned short s; } cv; cv.h = (_Float16)v; return cv.s;
}

// whQKV: f16 [384][128] (q rows pre-scaled by log2e/sqrt(hd))
// whP  : f16 [128][128]
// biasT: f32 [wtype][head][i][j], pre-scaled by log2e (incl. masks)
__global__ void prep2(const float* __restrict__ rpb,
                      const float* __restrict__ w_qkv,
                      const float* __restrict__ w_proj,
                      unsigned short* __restrict__ whQKV,
                      unsigned short* __restrict__ whP,
                      float* __restrict__ biasT)
{
    int idx = blockIdx.x * 256 + threadIdx.x;               // 131072 total
    if (idx < 49152) {
        float v = w_qkv[idx];
        if (idx < 16384) v *= SCALE_Q * LOG2E;              // q rows, log2e folded
        whQKV[idx] = f16b(v);
    } else if (idx < 65536) {
        int j = idx - 49152;
        whP[j] = f16b(w_proj[j]);
    } else {
        int k = idx - 65536;                                // 65536 bias elems
        int j = k & 63, i = (k >> 6) & 63, h = (k >> 12) & 3, t = k >> 14;
        float v;
        if (j >= 49)      v = -1e30f;                       // key padding
        else if (i >= 49) v = 0.f;                          // query padding (don't care)
        else {
            int ri = i / 7, ci = i % 7, rj = j / 7, cj = j % 7;
            int rel = (ri - rj + 6) * 13 + (ci - cj + 6);
            v = rpb[rel * 4 + h];
            int gi = ((t & 2) ? (ri < 4 ? 1 : 2) : 0) * 3 + ((t & 1) ? (ci < 4 ? 1 : 2) : 0);
            int gj = ((t & 2) ? (rj < 4 ? 1 : 2) : 0) * 3 + ((t & 1) ? (cj < 4 ? 1 : 2) : 0);
            if (gi != gj) v -= 100.f;
        }
        biasT[k] = v * LOG2E;                               // log2e folded
    }
}

__global__ __launch_bounds__(256, 4)
void swin_msa_mfma15(const float* __restrict__ x,
                     const unsigned short* __restrict__ whQKV,
                     const unsigned short* __restrict__ whP,
                     const float* __restrict__ b_proj,
                     const float* __restrict__ biasT,
                     float* __restrict__ out)
{
    // Xs: f16 window input [tok 0..63][ch 0..127], stride XS=140 halves.
    // Osh: attention output exchange, same geometry.
    __shared__ __align__(16) unsigned short Xs[64 * XS];     // 17920 B
    __shared__ __align__(16) unsigned short Osh[64 * XS];    // 17920 B

    const int tid  = threadIdx.x;
    const int h    = tid >> 6;         // wave id == head
    const int lane = tid & 63;
    const int c    = lane & 15;
    const int g    = lane >> 4;

    const int blk  = blockIdx.x;
    const int b    = blk >> 6;
    const int wIdx = blk & 63;
    const int wh   = wIdx >> 3, ww = wIdx & 7;
    const int wtype = ((wh == 7) ? 2 : 0) | ((ww == 7) ? 1 : 0);

    auto tokAddr = [&](int tok) {      // tok must be < 49
        int rr = tok / 7, cc = tok - rr * 7;
        int sh = wh * 7 + rr + 3; if (sh >= HWD) sh -= HWD;
        int sw = ww * 7 + cc + 3; if (sw >= HWD) sw -= HWD;
        return ((b * HWD + sh) * HWD + sw) * 128;
    };

    // ---- stage X: coalesced (32 lanes cover one 512B token row), f32->f16
    for (int idx = tid; idx < 2048; idx += 256) {
        int tok = idx >> 5, ch4 = (idx & 31) << 2;
        uint2 wv = make_uint2(0u, 0u);                      // zero pad rows 49..63
        if (tok < 49) {
            const float4 v = *(const float4*)(x + tokAddr(tok) + ch4);
            wv = make_uint2(pkrtz(v.x, v.y), pkrtz(v.z, v.w));
        }
        *(uint2*)&Xs[tok * XS + ch4] = wv;
    }
    __syncthreads();                   // barrier 1: X ready

    const int srcA  = c | ((lane & 16) << 1);  // lane (c, 2*(g&1))
    const int srcB  = srcA + 16;               // lane (c, 2*(g&1)+1)
    const bool hiSel = (lane & 32) != 0;       // g>>1 selects the tile-pair member

    // D->frag redistribution template (verified rounds 4..20):
    auto redist = [&](const unsigned pkLo[2], const unsigned pkHi[2], unsigned f[4]) {
        #pragma unroll
        for (int p = 0; p < 2; ++p) {
            unsigned lo0 = __shfl(pkLo[p], srcA);
            unsigned hi0 = __shfl(pkHi[p], srcA);
            f[p] = hiSel ? hi0 : lo0;
            unsigned lo1 = __shfl(pkLo[p], srcB);
            unsigned hi1 = __shfl(pkHi[p], srcB);
            f[2 + p] = hiSel ? hi1 : lo1;
        }
    };
    auto loadW = [&](const unsigned short* wbase, int rowBase, unsigned af[4][4]) {
        const unsigned short* wr = wbase + (rowBase + c) * 128 + g * 8;
        #pragma unroll
        for (int kk = 0; kk < 4; ++kk) {
            uint4 v = *(const uint4*)(wr + kk * 32);
            af[kk][0] = v.x; af[kk][1] = v.y; af[kk][2] = v.z; af[kk][3] = v.w;
        }
    };
    // X fragment from LDS via b64 pairs (stride 140 halves -> 4-way banks)
    auto xfrag = [&](int nt, unsigned xB[4][4]) {
        const unsigned short* xr = &Xs[(nt * 16 + c) * XS + g * 8];
        #pragma unroll
        for (int kk = 0; kk < 4; ++kk) {
            uint2 lo = *(const uint2*)(xr + kk * 32);
            uint2 hi = *(const uint2*)(xr + kk * 32 + 4);
            xB[kk][0] = lo.x; xB[kk][1] = lo.y; xB[kk][2] = hi.x; xB[kk][3] = hi.y;
        }
    };

    // ================= phase A: own-head Q,K,V (paired streams) ========
    unsigned qB[4][4];                 // B[k=d][n=i] per i-tile nt
    unsigned kA[4][4];                 // A[m=j][k=d] per j-tile mt
    unsigned vA[2][2][4];              // A[m=d][k=j] per (d-tile, j-chunk)
    {
        unsigned pkP[2][4][2];
        unsigned af0[4][4], af1[4][4];
        // --- Q: both ql streams loaded together, MFMA chains interleaved
        loadW(whQKV, 32 * h,      af0);
        loadW(whQKV, 32 * h + 16, af1);
        #pragma unroll
        for (int nt = 0; nt < 4; ++nt) {
            unsigned xB[4][4]; xfrag(nt, xB);
            f32x4 a0 = {0.f, 0.f, 0.f, 0.f};
            f32x4 a1 = {0.f, 0.f, 0.f, 0.f};
            #pragma unroll
            for (int kk = 0; kk < 4; ++kk) {
                a0 = mfma16(af0[kk], xB[kk], a0);
                a1 = mfma16(af1[kk], xB[kk], a1);
            }
            pkP[0][nt][0] = pkrtz(a0[0], a0[1]); pkP[0][nt][1] = pkrtz(a0[2], a0[3]);
            pkP[1][nt][0] = pkrtz(a1[0], a1[1]); pkP[1][nt][1] = pkrtz(a1[2], a1[3]);
        }
        #pragma unroll
        for (int nt = 0; nt < 4; ++nt) redist(pkP[0][nt], pkP[1][nt], qB[nt]);

        // --- K: paired kl streams
        loadW(whQKV, 128 + 32 * h,      af0);
        loadW(whQKV, 128 + 32 * h + 16, af1);
        #pragma unroll
        for (int mt = 0; mt < 4; ++mt) {
            unsigned xB[4][4]; xfrag(mt, xB);
            f32x4 a0 = {0.f, 0.f, 0.f, 0.f};
            f32x4 a1 = {0.f, 0.f, 0.f, 0.f};
            #pragma unroll
            for (int kk = 0; kk < 4; ++kk) {
                a0 = mfma16(af0[kk], xB[kk], a0);
                a1 = mfma16(af1[kk], xB[kk], a1);
            }
            pkP[0][mt][0] = pkrtz(a0[0], a0[1]); pkP[0][mt][1] = pkrtz(a0[2], a0[3]);
            pkP[1][mt][0] = pkrtz(a1[0], a1[1]); pkP[1][mt][1] = pkrtz(a1[2], a1[3]);
        }
        #pragma unroll
        for (int mt = 0; mt < 4; ++mt) redist(pkP[0][mt], pkP[1][mt], kA[mt]);

        // --- V: paired vl streams; mfma(X, Wv) -> D[tok][d]
        loadW(whQKV, 256 + 32 * h,      af0);
        loadW(whQKV, 256 + 32 * h + 16, af1);
        unsigned pkV0[4][2], pkV1[4][2];
        #pragma unroll
        for (int mt = 0; mt < 4; ++mt) {
            unsigned xA[4][4]; xfrag(mt, xA);
            f32x4 a0 = {0.f, 0.f, 0.f, 0.f};
            f32x4 a1 = {0.f, 0.f, 0.f, 0.f};
            #pragma unroll
            for (int kk = 0; kk < 4; ++kk) {
                a0 = mfma16(xA[kk], af0[kk], a0);
                a1 = mfma16(xA[kk], af1[kk], a1);
            }
            pkV0[mt][0] = pkrtz(a0[0], a0[1]); pkV0[mt][1] = pkrtz(a0[2], a0[3]);
            pkV1[mt][0] = pkrtz(a1[0], a1[1]); pkV1[mt][1] = pkrtz(a1[2], a1[3]);
        }
        #pragma unroll
        for (int kv = 0; kv < 2; ++kv) {
            redist(pkV0[2 * kv], pkV0[2 * kv + 1], vA[0][kv]);
            redist(pkV1[2 * kv], pkV1[2 * kv + 1], vA[1][kv]);
        }
    }

    // ================= attention: per-i-tile fused, bias pipelined =========
    const float* bT = biasT + (wtype * 4 + h) * 4096;       // [i][j] (log2e-scaled)
    float4 bias4[4];
    #pragma unroll
    for (int mt = 0; mt < 4; ++mt)
        bias4[mt] = *(const float4*)&bT[(0 * 16 + c) * 64 + mt * 16 + 4 * g];

    #pragma unroll
    for (int nt = 0; nt < 4; ++nt) {
        float4 biasN[4];
        if (nt < 3) {                  // prefetch next i-tile's bias early
            #pragma unroll
            for (int mt = 0; mt < 4; ++mt)
                biasN[mt] = *(const float4*)&bT[((nt + 1) * 16 + c) * 64 + mt * 16 + 4 * g];
        }
        f32x4 S[4];                    // S^T * log2e: lane j=16mt+4g+r, i=16nt+c
        #pragma unroll
        for (int mt = 0; mt < 4; ++mt) {
            f32x4 C = { bias4[mt].x, bias4[mt].y, bias4[mt].z, bias4[mt].w };
            S[mt] = mfma16(kA[mt], qB[nt], C);
        }
        // softmax over j: balanced-tree max + exp2 (log2e pre-folded)
        float m0 = fmaxf(fmaxf(S[0][0], S[0][1]), fmaxf(S[0][2], S[0][3]));
        float m1 = fmaxf(fmaxf(S[1][0], S[1][1]), fmaxf(S[1][2], S[1][3]));
        float m2 = fmaxf(fmaxf(S[2][0], S[2][1]), fmaxf(S[2][2], S[2][3]));
        float m3 = fmaxf(fmaxf(S[3][0], S[3][1]), fmaxf(S[3][2], S[3][3]));
        float m = fmaxf(fmaxf(m0, m1), fmaxf(m2, m3));
        m = fmaxf(m, __shfl_xor(m, 16));
        m = fmaxf(m, __shfl_xor(m, 32));
        float sp[4];
        #pragma unroll
        for (int mt = 0; mt < 4; ++mt) {
            #pragma unroll
            for (int r = 0; r < 4; ++r) S[mt][r] = exp2fast(S[mt][r] - m);
            sp[mt] = (S[mt][0] + S[mt][1]) + (S[mt][2] + S[mt][3]);
        }
        float s = (sp[0] + sp[1]) + (sp[2] + sp[3]);
        s += __shfl_xor(s, 16);
        s += __shfl_xor(s, 32);
        const float iv = 1.0f / s;     // applied at the O store (defer-norm)

        // PV on UNNORMALIZED P (exp2 <= 1, f16-safe): pack, redist, mfma
        f32x4 o0 = {0.f, 0.f, 0.f, 0.f};
        f32x4 o1 = {0.f, 0.f, 0.f, 0.f};
        #pragma unroll
        for (int kk = 0; kk < 2; ++kk) {
            unsigned pkLo[2], pkHi[2];
            pkLo[0] = pkrtz(S[2 * kk][0],     S[2 * kk][1]);
            pkLo[1] = pkrtz(S[2 * kk][2],     S[2 * kk][3]);
            pkHi[0] = pkrtz(S[2 * kk + 1][0], S[2 * kk + 1][1]);
            pkHi[1] = pkrtz(S[2 * kk + 1][2], S[2 * kk + 1][3]);
            unsigned pB[4];
            redist(pkLo, pkHi, pB);
            o0 = mfma16(vA[0][kk], pB, o0);
            o1 = mfma16(vA[1][kk], pB, o1);
        }
        // O-tile nt complete -> normalize at store
        *(uint2*)&Osh[(nt * 16 + c) * XS + 32 * h + 4 * g] =
            make_uint2(pkrtz(o0[0] * iv, o0[1] * iv), pkrtz(o0[2] * iv, o0[3] * iv));
        *(uint2*)&Osh[(nt * 16 + c) * XS + 32 * h + 16 + 4 * g] =
            make_uint2(pkrtz(o1[0] * iv, o1[1] * iv), pkrtz(o1[2] * iv, o1[3] * iv));
        if (nt < 3) {
            #pragma unroll
            for (int mt = 0; mt < 4; ++mt) bias4[mt] = biasN[mt];
        }
    }

    // ---- out-proj prefetch BEFORE the barrier: loads can't be hoisted
    //      across __syncthreads, so issue them here to overlap the wait.
    int taddr[4];
    #pragma unroll
    for (int nt = 0; nt < 4; ++nt) {
        int tok = nt * 16 + c;
        taddr[nt] = (tok < 49) ? tokAddr(tok) : -1;
    }
    unsigned aW0[4][4], aW1[4][4];
    loadW(whP, 16 * (2 * h),     aW0);
    loadW(whP, 16 * (2 * h + 1), aW1);
    float4 bb0 = *(const float4*)(b_proj + (2 * h) * 16 + 4 * g);
    float4 bb1 = *(const float4*)(b_proj + (2 * h + 1) * 16 + 4 * g);
    __syncthreads();                   // barrier 2: O ready

    // ================= out-proj: OUT = O @ Wproj^T + b (paired aW) =========
    #pragma unroll
    for (int nt = 0; nt < 4; ++nt) {
        unsigned oB[4][4];             // B[k=d][n=i] from O[i][d], this nt only
        {
            const unsigned short* orow = &Osh[(nt * 16 + c) * XS + g * 8];
            #pragma unroll
            for (int kk = 0; kk < 4; ++kk) {
                uint2 lo = *(const uint2*)(orow + kk * 32);
                uint2 hi = *(const uint2*)(orow + kk * 32 + 4);
                oB[kk][0] = lo.x; oB[kk][1] = lo.y; oB[kk][2] = hi.x; oB[kk][3] = hi.y;
            }
        }
        f32x4 a0 = {0.f, 0.f, 0.f, 0.f};
        f32x4 a1 = {0.f, 0.f, 0.f, 0.f};
        #pragma unroll
        for (int kk = 0; kk < 4; ++kk) {
            a0 = mfma16(aW0[kk], oB[kk], a0);
            a1 = mfma16(aW1[kk], oB[kk], a1);
        }
        if (taddr[nt] >= 0) {
            *(float4*)(out + taddr[nt] + (2 * h) * 16 + 4 * g) =
                make_float4(a0[0] + bb0.x, a0[1] + bb0.y, a0[2] + bb0.z, a0[3] + bb0.w);
            *(float4*)(out + taddr[nt] + (2 * h + 1) * 16 + 4 * g) =
                make_float4(a1[0] + bb1.x, a1[1] + bb1.y, a1[2] + bb1.z, a1[3] + bb1.w);
        }
    }
}

extern "C" void kernel_launch(void* const* d_in, const int* in_sizes, int n_in,
                              void* d_out, int out_size, void* d_ws, size_t ws_size,
                              hipStream_t stream) {
    const float* x     = (const float*)d_in[0];
    const float* rpb   = (const float*)d_in[1];
    const float* wqkv  = (const float*)d_in[2];
    const float* wproj = (const float*)d_in[3];
    const float* bproj = (const float*)d_in[4];
    float* outp = (float*)d_out;

    unsigned short* whQKV = (unsigned short*)d_ws;          // 49152 halves
    unsigned short* whP   = whQKV + 49152;                  // 16384 halves
    float* biasT = (float*)(whP + 16384);                   // 65536 f32

    prep2<<<512, 256, 0, stream>>>(rpb, wqkv, wproj, whQKV, whP, biasT);
    swin_msa_mfma15<<<32 * 64, 256, 0, stream>>>(x, whQKV, whP, bproj, biasT, outp);
}

// Round 22
// 63.113 us; speedup vs baseline: 1.1709x; 1.1709x over previous
//
#include <hip/hip_runtime.h>

// Fused Swin shifted-window MSA, one workgroup (4 waves) per 7x7 window.
// Round 22: FINAL — revert byte-identical to round 20 (best passing, 63.36us).
// r21's A/B proved s_setprio is load-bearing here as a COMPILER SCHEDULING
// FENCE: removing it let the scheduler extend live ranges past the 128-reg
// cap (WRITE 50->109MB = spills, +10.5us). Keep it.
// Config: max-pass exp2 softmax (log2e folded into q-scale + bias table),
// defer-normalize (1/s at O store), LDS stride 140 + b64 frag reads (4-way
// banks), paired weight streams, bias double-buffer, out-proj prefetch
// before barrier 2, s_setprio around MFMA clusters.
// Ladder: 916 (r1 VALU) -> 101 (r3 MFMA) -> 88 -> 73 -> 69 -> 65.1 (r10)
// -> 64.9 (r14 bank-conflict fix) -> 63.4 (r16 exp2+prefetch). 14.4x total.

#define HWD 56
#define SCALE_Q 0.17677669529663687f   // 1/sqrt(32)
#define LOG2E   1.4426950408889634f
#define XS 140                          // LDS row stride in halves (70 words)

typedef _Float16 f16x8 __attribute__((ext_vector_type(8)));
typedef __fp16   h16x2 __attribute__((ext_vector_type(2)));   // cvt_pkrtz return type
typedef float    f32x4 __attribute__((ext_vector_type(4)));

__device__ __forceinline__ unsigned pkrtz(float a, float b) {
    union { h16x2 h; unsigned u; } r;
    r.h = __builtin_amdgcn_cvt_pkrtz(a, b);
    return r.u;
}

__device__ __forceinline__ float exp2fast(float x) {   // v_exp_f32: D = 2^S0
    float r;
    asm("v_exp_f32 %0, %1" : "=v"(r) : "v"(x));
    return r;
}

__device__ __forceinline__ f32x4 mfma16(const unsigned a[4], const unsigned b[4], f32x4 c) {
    union { unsigned u[4]; f16x8 h; } A, B;
    A.u[0] = a[0]; A.u[1] = a[1]; A.u[2] = a[2]; A.u[3] = a[3];
    B.u[0] = b[0]; B.u[1] = b[1]; B.u[2] = b[2]; B.u[3] = b[3];
    return __builtin_amdgcn_mfma_f32_16x16x32_f16(A.h, B.h, c, 0, 0, 0);
}

__device__ __forceinline__ unsigned short f16b(float v) {
    union { _Float16 h; unsigned short s; } cv; cv.h = (_Float16)v; return cv.s;
}

// whQKV: f16 [384][128] (q rows pre-scaled by log2e/sqrt(hd))
// whP  : f16 [128][128]
// biasT: f32 [wtype][head][i][j], pre-scaled by log2e (incl. masks)
__global__ void prep2(const float* __restrict__ rpb,
                      const float* __restrict__ w_qkv,
                      const float* __restrict__ w_proj,
                      unsigned short* __restrict__ whQKV,
                      unsigned short* __restrict__ whP,
                      float* __restrict__ biasT)
{
    int idx = blockIdx.x * 256 + threadIdx.x;               // 131072 total
    if (idx < 49152) {
        float v = w_qkv[idx];
        if (idx < 16384) v *= SCALE_Q * LOG2E;              // q rows, log2e folded
        whQKV[idx] = f16b(v);
    } else if (idx < 65536) {
        int j = idx - 49152;
        whP[j] = f16b(w_proj[j]);
    } else {
        int k = idx - 65536;                                // 65536 bias elems
        int j = k & 63, i = (k >> 6) & 63, h = (k >> 12) & 3, t = k >> 14;
        float v;
        if (j >= 49)      v = -1e30f;                       // key padding
        else if (i >= 49) v = 0.f;                          // query padding (don't care)
        else {
            int ri = i / 7, ci = i % 7, rj = j / 7, cj = j % 7;
            int rel = (ri - rj + 6) * 13 + (ci - cj + 6);
            v = rpb[rel * 4 + h];
            int gi = ((t & 2) ? (ri < 4 ? 1 : 2) : 0) * 3 + ((t & 1) ? (ci < 4 ? 1 : 2) : 0);
            int gj = ((t & 2) ? (rj < 4 ? 1 : 2) : 0) * 3 + ((t & 1) ? (cj < 4 ? 1 : 2) : 0);
            if (gi != gj) v -= 100.f;
        }
        biasT[k] = v * LOG2E;                               // log2e folded
    }
}

__global__ __launch_bounds__(256, 4)
void swin_msa_mfma13(const float* __restrict__ x,
                     const unsigned short* __restrict__ whQKV,
                     const unsigned short* __restrict__ whP,
                     const float* __restrict__ b_proj,
                     const float* __restrict__ biasT,
                     float* __restrict__ out)
{
    // Xs: f16 window input [tok 0..63][ch 0..127], stride XS=140 halves.
    // Osh: attention output exchange, same geometry.
    __shared__ __align__(16) unsigned short Xs[64 * XS];     // 17920 B
    __shared__ __align__(16) unsigned short Osh[64 * XS];    // 17920 B

    const int tid  = threadIdx.x;
    const int h    = tid >> 6;         // wave id == head
    const int lane = tid & 63;
    const int c    = lane & 15;
    const int g    = lane >> 4;

    const int blk  = blockIdx.x;
    const int b    = blk >> 6;
    const int wIdx = blk & 63;
    const int wh   = wIdx >> 3, ww = wIdx & 7;
    const int wtype = ((wh == 7) ? 2 : 0) | ((ww == 7) ? 1 : 0);

    auto tokAddr = [&](int tok) {      // tok must be < 49
        int rr = tok / 7, cc = tok - rr * 7;
        int sh = wh * 7 + rr + 3; if (sh >= HWD) sh -= HWD;
        int sw = ww * 7 + cc + 3; if (sw >= HWD) sw -= HWD;
        return ((b * HWD + sh) * HWD + sw) * 128;
    };

    // ---- stage X: coalesced (32 lanes cover one 512B token row), f32->f16
    for (int idx = tid; idx < 2048; idx += 256) {
        int tok = idx >> 5, ch4 = (idx & 31) << 2;
        uint2 wv = make_uint2(0u, 0u);                      // zero pad rows 49..63
        if (tok < 49) {
            const float4 v = *(const float4*)(x + tokAddr(tok) + ch4);
            wv = make_uint2(pkrtz(v.x, v.y), pkrtz(v.z, v.w));
        }
        *(uint2*)&Xs[tok * XS + ch4] = wv;
    }
    __syncthreads();                   // barrier 1: X ready

    const int srcA  = c | ((lane & 16) << 1);  // lane (c, 2*(g&1))
    const int srcB  = srcA + 16;               // lane (c, 2*(g&1)+1)
    const bool hiSel = (lane & 32) != 0;       // g>>1 selects the tile-pair member

    // D->frag redistribution template (verified rounds 4..20):
    auto redist = [&](const unsigned pkLo[2], const unsigned pkHi[2], unsigned f[4]) {
        #pragma unroll
        for (int p = 0; p < 2; ++p) {
            unsigned lo0 = __shfl(pkLo[p], srcA);
            unsigned hi0 = __shfl(pkHi[p], srcA);
            f[p] = hiSel ? hi0 : lo0;
            unsigned lo1 = __shfl(pkLo[p], srcB);
            unsigned hi1 = __shfl(pkHi[p], srcB);
            f[2 + p] = hiSel ? hi1 : lo1;
        }
    };
    auto loadW = [&](const unsigned short* wbase, int rowBase, unsigned af[4][4]) {
        const unsigned short* wr = wbase + (rowBase + c) * 128 + g * 8;
        #pragma unroll
        for (int kk = 0; kk < 4; ++kk) {
            uint4 v = *(const uint4*)(wr + kk * 32);
            af[kk][0] = v.x; af[kk][1] = v.y; af[kk][2] = v.z; af[kk][3] = v.w;
        }
    };
    // X fragment from LDS via b64 pairs (stride 140 halves -> 4-way banks)
    auto xfrag = [&](int nt, unsigned xB[4][4]) {
        const unsigned short* xr = &Xs[(nt * 16 + c) * XS + g * 8];
        #pragma unroll
        for (int kk = 0; kk < 4; ++kk) {
            uint2 lo = *(const uint2*)(xr + kk * 32);
            uint2 hi = *(const uint2*)(xr + kk * 32 + 4);
            xB[kk][0] = lo.x; xB[kk][1] = lo.y; xB[kk][2] = hi.x; xB[kk][3] = hi.y;
        }
    };

    // ================= phase A: own-head Q,K,V (paired streams) ========
    unsigned qB[4][4];                 // B[k=d][n=i] per i-tile nt
    unsigned kA[4][4];                 // A[m=j][k=d] per j-tile mt
    unsigned vA[2][2][4];              // A[m=d][k=j] per (d-tile, j-chunk)
    {
        unsigned pkP[2][4][2];
        unsigned af0[4][4], af1[4][4];
        // --- Q: both ql streams loaded together, MFMA chains interleaved
        loadW(whQKV, 32 * h,      af0);
        loadW(whQKV, 32 * h + 16, af1);
        __builtin_amdgcn_s_setprio(1);
        #pragma unroll
        for (int nt = 0; nt < 4; ++nt) {
            unsigned xB[4][4]; xfrag(nt, xB);
            f32x4 a0 = {0.f, 0.f, 0.f, 0.f};
            f32x4 a1 = {0.f, 0.f, 0.f, 0.f};
            #pragma unroll
            for (int kk = 0; kk < 4; ++kk) {
                a0 = mfma16(af0[kk], xB[kk], a0);
                a1 = mfma16(af1[kk], xB[kk], a1);
            }
            pkP[0][nt][0] = pkrtz(a0[0], a0[1]); pkP[0][nt][1] = pkrtz(a0[2], a0[3]);
            pkP[1][nt][0] = pkrtz(a1[0], a1[1]); pkP[1][nt][1] = pkrtz(a1[2], a1[3]);
        }
        __builtin_amdgcn_s_setprio(0);
        #pragma unroll
        for (int nt = 0; nt < 4; ++nt) redist(pkP[0][nt], pkP[1][nt], qB[nt]);

        // --- K: paired kl streams
        loadW(whQKV, 128 + 32 * h,      af0);
        loadW(whQKV, 128 + 32 * h + 16, af1);
        __builtin_amdgcn_s_setprio(1);
        #pragma unroll
        for (int mt = 0; mt < 4; ++mt) {
            unsigned xB[4][4]; xfrag(mt, xB);
            f32x4 a0 = {0.f, 0.f, 0.f, 0.f};
            f32x4 a1 = {0.f, 0.f, 0.f, 0.f};
            #pragma unroll
            for (int kk = 0; kk < 4; ++kk) {
                a0 = mfma16(af0[kk], xB[kk], a0);
                a1 = mfma16(af1[kk], xB[kk], a1);
            }
            pkP[0][mt][0] = pkrtz(a0[0], a0[1]); pkP[0][mt][1] = pkrtz(a0[2], a0[3]);
            pkP[1][mt][0] = pkrtz(a1[0], a1[1]); pkP[1][mt][1] = pkrtz(a1[2], a1[3]);
        }
        __builtin_amdgcn_s_setprio(0);
        #pragma unroll
        for (int mt = 0; mt < 4; ++mt) redist(pkP[0][mt], pkP[1][mt], kA[mt]);

        // --- V: paired vl streams; mfma(X, Wv) -> D[tok][d]
        loadW(whQKV, 256 + 32 * h,      af0);
        loadW(whQKV, 256 + 32 * h + 16, af1);
        unsigned pkV0[4][2], pkV1[4][2];
        __builtin_amdgcn_s_setprio(1);
        #pragma unroll
        for (int mt = 0; mt < 4; ++mt) {
            unsigned xA[4][4]; xfrag(mt, xA);
            f32x4 a0 = {0.f, 0.f, 0.f, 0.f};
            f32x4 a1 = {0.f, 0.f, 0.f, 0.f};
            #pragma unroll
            for (int kk = 0; kk < 4; ++kk) {
                a0 = mfma16(xA[kk], af0[kk], a0);
                a1 = mfma16(xA[kk], af1[kk], a1);
            }
            pkV0[mt][0] = pkrtz(a0[0], a0[1]); pkV0[mt][1] = pkrtz(a0[2], a0[3]);
            pkV1[mt][0] = pkrtz(a1[0], a1[1]); pkV1[mt][1] = pkrtz(a1[2], a1[3]);
        }
        __builtin_amdgcn_s_setprio(0);
        #pragma unroll
        for (int kv = 0; kv < 2; ++kv) {
            redist(pkV0[2 * kv], pkV0[2 * kv + 1], vA[0][kv]);
            redist(pkV1[2 * kv], pkV1[2 * kv + 1], vA[1][kv]);
        }
    }

    // ================= attention: per-i-tile fused, bias pipelined =========
    const float* bT = biasT + (wtype * 4 + h) * 4096;       // [i][j] (log2e-scaled)
    float4 bias4[4];
    #pragma unroll
    for (int mt = 0; mt < 4; ++mt)
        bias4[mt] = *(const float4*)&bT[(0 * 16 + c) * 64 + mt * 16 + 4 * g];

    #pragma unroll
    for (int nt = 0; nt < 4; ++nt) {
        float4 biasN[4];
        if (nt < 3) {                  // prefetch next i-tile's bias early
            #pragma unroll
            for (int mt = 0; mt < 4; ++mt)
                biasN[mt] = *(const float4*)&bT[((nt + 1) * 16 + c) * 64 + mt * 16 + 4 * g];
        }
        f32x4 S[4];                    // S^T * log2e: lane j=16mt+4g+r, i=16nt+c
        __builtin_amdgcn_s_setprio(1);
        #pragma unroll
        for (int mt = 0; mt < 4; ++mt) {
            f32x4 C = { bias4[mt].x, bias4[mt].y, bias4[mt].z, bias4[mt].w };
            S[mt] = mfma16(kA[mt], qB[nt], C);
        }
        __builtin_amdgcn_s_setprio(0);
        // softmax over j: balanced-tree max + exp2 (log2e pre-folded)
        float m0 = fmaxf(fmaxf(S[0][0], S[0][1]), fmaxf(S[0][2], S[0][3]));
        float m1 = fmaxf(fmaxf(S[1][0], S[1][1]), fmaxf(S[1][2], S[1][3]));
        float m2 = fmaxf(fmaxf(S[2][0], S[2][1]), fmaxf(S[2][2], S[2][3]));
        float m3 = fmaxf(fmaxf(S[3][0], S[3][1]), fmaxf(S[3][2], S[3][3]));
        float m = fmaxf(fmaxf(m0, m1), fmaxf(m2, m3));
        m = fmaxf(m, __shfl_xor(m, 16));
        m = fmaxf(m, __shfl_xor(m, 32));
        float sp[4];
        #pragma unroll
        for (int mt = 0; mt < 4; ++mt) {
            #pragma unroll
            for (int r = 0; r < 4; ++r) S[mt][r] = exp2fast(S[mt][r] - m);
            sp[mt] = (S[mt][0] + S[mt][1]) + (S[mt][2] + S[mt][3]);
        }
        float s = (sp[0] + sp[1]) + (sp[2] + sp[3]);
        s += __shfl_xor(s, 16);
        s += __shfl_xor(s, 32);
        const float iv = 1.0f / s;     // applied at the O store (defer-norm)

        // PV on UNNORMALIZED P (exp2 <= 1, f16-safe): pack, redist, mfma
        f32x4 o0 = {0.f, 0.f, 0.f, 0.f};
        f32x4 o1 = {0.f, 0.f, 0.f, 0.f};
        #pragma unroll
        for (int kk = 0; kk < 2; ++kk) {
            unsigned pkLo[2], pkHi[2];
            pkLo[0] = pkrtz(S[2 * kk][0],     S[2 * kk][1]);
            pkLo[1] = pkrtz(S[2 * kk][2],     S[2 * kk][3]);
            pkHi[0] = pkrtz(S[2 * kk + 1][0], S[2 * kk + 1][1]);
            pkHi[1] = pkrtz(S[2 * kk + 1][2], S[2 * kk + 1][3]);
            unsigned pB[4];
            redist(pkLo, pkHi, pB);
            __builtin_amdgcn_s_setprio(1);
            o0 = mfma16(vA[0][kk], pB, o0);
            o1 = mfma16(vA[1][kk], pB, o1);
            __builtin_amdgcn_s_setprio(0);
        }
        // O-tile nt complete -> normalize at store
        *(uint2*)&Osh[(nt * 16 + c) * XS + 32 * h + 4 * g] =
            make_uint2(pkrtz(o0[0] * iv, o0[1] * iv), pkrtz(o0[2] * iv, o0[3] * iv));
        *(uint2*)&Osh[(nt * 16 + c) * XS + 32 * h + 16 + 4 * g] =
            make_uint2(pkrtz(o1[0] * iv, o1[1] * iv), pkrtz(o1[2] * iv, o1[3] * iv));
        if (nt < 3) {
            #pragma unroll
            for (int mt = 0; mt < 4; ++mt) bias4[mt] = biasN[mt];
        }
    }

    // ---- out-proj prefetch BEFORE the barrier: loads can't be hoisted
    //      across __syncthreads, so issue them here to overlap the wait.
    int taddr[4];
    #pragma unroll
    for (int nt = 0; nt < 4; ++nt) {
        int tok = nt * 16 + c;
        taddr[nt] = (tok < 49) ? tokAddr(tok) : -1;
    }
    unsigned aW0[4][4], aW1[4][4];
    loadW(whP, 16 * (2 * h),     aW0);
    loadW(whP, 16 * (2 * h + 1), aW1);
    float4 bb0 = *(const float4*)(b_proj + (2 * h) * 16 + 4 * g);
    float4 bb1 = *(const float4*)(b_proj + (2 * h + 1) * 16 + 4 * g);
    __syncthreads();                   // barrier 2: O ready

    // ================= out-proj: OUT = O @ Wproj^T + b (paired aW) =========
    #pragma unroll
    for (int nt = 0; nt < 4; ++nt) {
        unsigned oB[4][4];             // B[k=d][n=i] from O[i][d], this nt only
        {
            const unsigned short* orow = &Osh[(nt * 16 + c) * XS + g * 8];
            #pragma unroll
            for (int kk = 0; kk < 4; ++kk) {
                uint2 lo = *(const uint2*)(orow + kk * 32);
                uint2 hi = *(const uint2*)(orow + kk * 32 + 4);
                oB[kk][0] = lo.x; oB[kk][1] = lo.y; oB[kk][2] = hi.x; oB[kk][3] = hi.y;
            }
        }
        f32x4 a0 = {0.f, 0.f, 0.f, 0.f};
        f32x4 a1 = {0.f, 0.f, 0.f, 0.f};
        __builtin_amdgcn_s_setprio(1);
        #pragma unroll
        for (int kk = 0; kk < 4; ++kk) {
            a0 = mfma16(aW0[kk], oB[kk], a0);
            a1 = mfma16(aW1[kk], oB[kk], a1);
        }
        __builtin_amdgcn_s_setprio(0);
        if (taddr[nt] >= 0) {
            *(float4*)(out + taddr[nt] + (2 * h) * 16 + 4 * g) =
                make_float4(a0[0] + bb0.x, a0[1] + bb0.y, a0[2] + bb0.z, a0[3] + bb0.w);
            *(float4*)(out + taddr[nt] + (2 * h + 1) * 16 + 4 * g) =
                make_float4(a1[0] + bb1.x, a1[1] + bb1.y, a1[2] + bb1.z, a1[3] + bb1.w);
        }
    }
}

extern "C" void kernel_launch(void* const* d_in, const int* in_sizes, int n_in,
                              void* d_out, int out_size, void* d_ws, size_t ws_size,
                              hipStream_t stream) {
    const float* x     = (const float*)d_in[0];
    const float* rpb   = (const float*)d_in[1];
    const float* wqkv  = (const float*)d_in[2];
    const float* wproj = (const float*)d_in[3];
    const float* bproj = (const float*)d_in[4];
    float* outp = (float*)d_out;

    unsigned short* whQKV = (unsigned short*)d_ws;          // 49152 halves
    unsigned short* whP   = whQKV + 49152;                  // 16384 halves
    float* biasT = (float*)(whP + 16384);                   // 65536 f32

    prep2<<<512, 256, 0, stream>>>(rpb, wqkv, wproj, whQKV, whP, biasT);
    swin_msa_mfma13<<<32 * 64, 256, 0, stream>>>(x, whQKV, whP, bproj, biasT, outp);
}